// Round 3
// baseline (353.510 us; speedup 1.0000x reference)
//
#include <hip/hip_runtime.h>
#include <math.h>

// MultiLocalCosineLinear: B=65536 rows, D=768, C=100, P=4950 pairs.
// out layout (all float32): [0..B)  = preds (class id as float)
//                           [B..3B) = logits, row-major (B,2)
//
// R2: latency-bound fix. K3 processes 2 rows/wave (18 float4 loads in
// flight, interleaved reduction chains, 2-lane epilogue) with nontemporal
// x loads to keep weights L2/L3-resident. K2 does 2 rows/wave with
// width-32 shuffles (5 merge steps).

#define D_DIM 768
#define C_DIM 100
#define P_DIM 4950               // C*(C-1)/2
#define F4_PER_ROW (D_DIM / 4)   // 192
#define EPS_N 1e-12

typedef float vf4 __attribute__((ext_vector_type(4)));

__device__ __forceinline__ bool vi_gt(float v0, int i0, float v1, int i1) {
    // lexicographic (value desc, index asc) — matches jax.lax.top_k tie rules
    return (v0 > v1) || (v0 == v1 && i0 < i1);
}

// ---------------- K1: weight inverse norms (f64 exact) ----------------
// one wave per weight vector; 2P = 9900 vectors
__global__ __launch_bounds__(256) void norm_kernel(
    const float* __restrict__ weights,
    double* __restrict__ invn,
    int nrows)
{
    const int lane = threadIdx.x & 63;
    const int row = (blockIdx.x << 2) + (threadIdx.x >> 6);
    if (row >= nrows) return;

    const vf4* wv = (const vf4*)(weights + (size_t)row * D_DIM);
    double n = 0.0;
    #pragma unroll
    for (int j = 0; j < 3; ++j) {
        vf4 w = wv[lane + j * 64];
        n += (double)w.x * w.x + (double)w.y * w.y
           + (double)w.z * w.z + (double)w.w * w.w;
    }
    #pragma unroll
    for (int m = 1; m < 64; m <<= 1) n += __shfl_xor(n, m, 64);
    if (lane == 0) invn[row] = 1.0 / fmax(sqrt(n), EPS_N);
}

// ---------------- K2: top-2 of first_out rows -> packed (a,b) ----------------
// 2 rows per wave: 32 lanes/row, 4 candidates/lane, 5-step width-32 merge
__global__ __launch_bounds__(256) void top2_kernel(
    const float* __restrict__ first_out,
    int* __restrict__ abbuf,
    int B)
{
    const int lane = threadIdx.x & 63;
    const int wave = threadIdx.x >> 6;
    const int l32 = lane & 31;
    const int r = (((blockIdx.x << 2) + wave) << 1) + (lane >> 5);
    if (r >= B) return;

    const float* fo = first_out + (size_t)r * C_DIM;

    float v1 = fo[l32]; int i1 = l32;
    float v2 = -INFINITY; int i2 = 0x7fffffff;
    {
        float e = fo[l32 + 32]; int ie = l32 + 32;
        if (vi_gt(e, ie, v1, i1)) { v2 = v1; i2 = i1; v1 = e; i1 = ie; }
        else if (vi_gt(e, ie, v2, i2)) { v2 = e; i2 = ie; }
    }
    {
        float e = fo[l32 + 64]; int ie = l32 + 64;
        if (vi_gt(e, ie, v1, i1)) { v2 = v1; i2 = i1; v1 = e; i1 = ie; }
        else if (vi_gt(e, ie, v2, i2)) { v2 = e; i2 = ie; }
    }
    if (l32 < 4) {
        float e = fo[l32 + 96]; int ie = l32 + 96;
        if (vi_gt(e, ie, v1, i1)) { v2 = v1; i2 = i1; v1 = e; i1 = ie; }
        else if (vi_gt(e, ie, v2, i2)) { v2 = e; i2 = ie; }
    }

    #pragma unroll
    for (int m = 1; m < 32; m <<= 1) {
        float ov1 = __shfl_xor(v1, m, 32);
        int   oi1 = __shfl_xor(i1, m, 32);
        float ov2 = __shfl_xor(v2, m, 32);
        int   oi2 = __shfl_xor(i2, m, 32);
        if (vi_gt(ov1, oi1, v1, i1)) {
            float nv2; int ni2;
            if (vi_gt(v1, i1, ov2, oi2)) { nv2 = v1;  ni2 = i1; }
            else                         { nv2 = ov2; ni2 = oi2; }
            v1 = ov1; i1 = oi1; v2 = nv2; i2 = ni2;
        } else {
            if (vi_gt(ov1, oi1, v2, i2)) { v2 = ov1; i2 = oi1; }
        }
    }
    if (l32 == 0) {
        const int a = min(i1, i2);
        const int b = max(i1, i2);
        abbuf[r] = a | (b << 16);
    }
}

// ---------------- K3: dots + logits + argmax, 2 rows per wave ----------------
__global__ __launch_bounds__(256) void main_kernel(
    const float* __restrict__ x,
    const float* __restrict__ weights,
    const float* __restrict__ sigma,
    const double* __restrict__ invn,
    const int* __restrict__ abbuf,
    float* __restrict__ out,
    int B)
{
    const int lane = threadIdx.x & 63;
    const int wave = threadIdx.x >> 6;
    const int base = ((blockIdx.x << 2) + wave) << 1;   // 2 rows per wave
    if (base >= B) return;                               // B even

    const int ab0 = abbuf[base];       // wave-uniform -> scalar load
    const int ab1 = abbuf[base + 1];
    const int a0 = ab0 & 0xffff, b0 = ab0 >> 16;
    const int a1 = ab1 & 0xffff, b1 = ab1 >> 16;
    const int p0 = b0 * (b0 - 1) / 2 + a0;
    const int p1 = b1 * (b1 - 1) / 2 + a1;

    const vf4* xv  = (const vf4*)(x + (size_t)base * D_DIM);           // rows base, base+1
    const vf4* w0v = (const vf4*)(weights + (size_t)p0 * (2 * D_DIM)); // row0's w0,w1
    const vf4* w1v = (const vf4*)(weights + (size_t)p1 * (2 * D_DIM)); // row1's w0,w1

    // xx in f32 (common positive scale, can't flip argmax); dots in f64.
    float  xx0 = 0.f, xx1 = 0.f;
    double d00 = 0.0, d01 = 0.0, d10 = 0.0, d11 = 0.0;
    #pragma unroll
    for (int j = 0; j < 3; ++j) {
        const int idx = lane + j * 64;
        vf4 xa = __builtin_nontemporal_load(xv + idx);               // x row0 (stream-once)
        vf4 xb = __builtin_nontemporal_load(xv + F4_PER_ROW + idx);  // x row1
        vf4 wa = w0v[idx];
        vf4 wb = w0v[F4_PER_ROW + idx];
        vf4 wc = w1v[idx];
        vf4 wd = w1v[F4_PER_ROW + idx];
        xx0 += xa.x * xa.x + xa.y * xa.y + xa.z * xa.z + xa.w * xa.w;
        xx1 += xb.x * xb.x + xb.y * xb.y + xb.z * xb.z + xb.w * xb.w;
        d00 += (double)xa.x * wa.x + (double)xa.y * wa.y
             + (double)xa.z * wa.z + (double)xa.w * wa.w;
        d01 += (double)xa.x * wb.x + (double)xa.y * wb.y
             + (double)xa.z * wb.z + (double)xa.w * wb.w;
        d10 += (double)xb.x * wc.x + (double)xb.y * wc.y
             + (double)xb.z * wc.z + (double)xb.w * wc.w;
        d11 += (double)xb.x * wd.x + (double)xb.y * wd.y
             + (double)xb.z * wd.z + (double)xb.w * wd.w;
    }
    #pragma unroll
    for (int m = 1; m < 64; m <<= 1) {
        xx0 += __shfl_xor(xx0, m, 64);
        xx1 += __shfl_xor(xx1, m, 64);
        d00 += __shfl_xor(d00, m, 64);
        d01 += __shfl_xor(d01, m, 64);
        d10 += __shfl_xor(d10, m, 64);
        d11 += __shfl_xor(d11, m, 64);
    }

    if (lane < 2) {   // lane 0 -> row base, lane 1 -> row base+1
        const int    rr  = base + lane;
        const int    p   = lane ? p1 : p0;
        const int    aa  = lane ? a1 : a0;
        const int    bb  = lane ? b1 : b0;
        const float  xxv = lane ? xx1 : xx0;
        const double dd0 = lane ? d10 : d00;
        const double dd1 = lane ? d11 : d01;
        const double s    = (double)sigma[p];
        const double sinx = s / fmax(sqrt((double)xxv), EPS_N);
        const double l0   = sinx * dd0 * invn[2 * p];
        const double l1   = sinx * dd1 * invn[2 * p + 1];
        const int sel = (l1 > l0) ? 1 : 0;   // jnp.argmax: first index wins ties
        out[rr] = (float)(sel ? bb : aa);
        out[B + 2 * rr]     = (float)l0;
        out[B + 2 * rr + 1] = (float)l1;
    }
}

extern "C" void kernel_launch(void* const* d_in, const int* in_sizes, int n_in,
                              void* d_out, int out_size, void* d_ws, size_t ws_size,
                              hipStream_t stream) {
    const float* x         = (const float*)d_in[0];
    const float* first_out = (const float*)d_in[1];
    const float* weights   = (const float*)d_in[2];
    const float* sigma     = (const float*)d_in[3];
    float* out = (float*)d_out;

    const int B  = in_sizes[0] / D_DIM;   // 65536
    const int NW = 2 * P_DIM;             // 9900 weight vectors

    // ws layout: [invn: 2P doubles][abbuf: B ints]  (~342 KB)
    double* invn = (double*)d_ws;
    int* abbuf   = (int*)((char*)d_ws + (size_t)NW * sizeof(double));

    hipLaunchKernelGGL(norm_kernel, dim3((NW + 3) / 4), dim3(256), 0, stream,
                       weights, invn, NW);
    hipLaunchKernelGGL(top2_kernel, dim3((B + 7) / 8), dim3(256), 0, stream,
                       first_out, abbuf, B);
    hipLaunchKernelGGL(main_kernel, dim3((B + 7) / 8), dim3(256), 0, stream,
                       x, weights, sigma, invn, abbuf, out, B);
}